// Round 5
// baseline (463.906 us; speedup 1.0000x reference)
//
#include <hip/hip_runtime.h>

#define SEQK 512
#define NH 16
#define HD 64
#define RD 1024
#define BBATCH 32
#define QK_SCALE 0.125f        // 1/sqrt(64)
#define LOG2E 1.4426950408889634f

typedef unsigned short u16;
typedef unsigned int u32;
using bf16x8 = __attribute__((ext_vector_type(8))) short;
using f32x4  = __attribute__((ext_vector_type(4))) float;
using f32x16 = __attribute__((ext_vector_type(16))) float;

__device__ __forceinline__ u16 f2bf(float f) {
  unsigned u = __float_as_uint(f);
  u += 0x7FFFu + ((u >> 16) & 1u);   // round-to-nearest-even
  return (u16)(u >> 16);
}
__device__ __forceinline__ float bf2f(u16 v) {
  return __uint_as_float(((unsigned)v) << 16);
}
// 2^x in one VALU op (inputs are pre-scaled by LOG2E upstream)
__device__ __forceinline__ float fexp2(float x) {
  float r;
  asm("v_exp_f32 %0, %1" : "=v"(r) : "v"(x));
  return r;
}
// packed f32x2 -> bf16x2 (RNE), lo in [15:0], hi in [31:16]  (m240 recipe)
__device__ __forceinline__ u32 pkbf(float lo, float hi) {
  u32 r;
  asm("v_cvt_pk_bf16_f32 %0, %1, %2" : "=v"(r) : "v"(lo), "v"(hi));
  return r;
}
// swap a's upper 32 lanes with b's lower 32 lanes (gfx950 permlane32_swap)
__device__ __forceinline__ void plswap(u32& a, u32& b) {
#if __has_builtin(__builtin_amdgcn_permlane32_swap)
  typedef int v2i __attribute__((ext_vector_type(2)));
  v2i r = __builtin_amdgcn_permlane32_swap((int)a, (int)b, false, false);
  a = (u32)r[0]; b = (u32)r[1];
#else
  asm volatile("v_permlane32_swap_b32 %0, %1" : "+v"(a), "+v"(b));
#endif
}

__device__ __forceinline__ void async_cp16(const void* g, void* l) {
  __builtin_amdgcn_global_load_lds(
      (__attribute__((address_space(1))) void*)(void*)g,
      (__attribute__((address_space(3))) void*)l,
      16, 0, 0);
}

// ---------------------------------------------------------------- convert
__global__ void convert_kernel(const float* __restrict__ hR,
                               const float* __restrict__ Wq, const float* __restrict__ Wk,
                               const float* __restrict__ Wv, const float* __restrict__ Wo,
                               u16* __restrict__ hR16,
                               u16* __restrict__ Wq16, u16* __restrict__ Wk16,
                               u16* __restrict__ Wv16, u16* __restrict__ Wo16) {
  size_t i4 = (size_t)blockIdx.x * blockDim.x + threadIdx.x;
  size_t e = i4 * 4;
  const float* src; u16* dst; size_t off;
  if (e < 16777216u) { src = hR; dst = hR16; off = e; }
  else {
    size_t r = e - 16777216u;
    int w = (int)(r >> 20);
    off = r & 1048575u;
    src = (w == 0 ? Wq : w == 1 ? Wk : w == 2 ? Wv : Wo);
    dst = (w == 0 ? Wq16 : w == 1 ? Wk16 : w == 2 ? Wv16 : Wo16);
  }
  float4 v = *(const float4*)(src + off);
  ushort4 o;
  o.x = f2bf(v.x); o.y = f2bf(v.y); o.z = f2bf(v.z); o.w = f2bf(v.w);
  *(ushort4*)(dst + off) = o;
}

// ---------------------------------------------------------------- R normalize
__global__ void rnorm_kernel(const float* __restrict__ R, float* __restrict__ Rn) {
  int row = blockIdx.x;
  int lane = threadIdx.x;
  float4 v = *(const float4*)(R + (size_t)row * 256 + lane * 4);
  float ss = v.x * v.x + v.y * v.y + v.z * v.z + v.w * v.w;
  for (int off = 32; off; off >>= 1) ss += __shfl_xor(ss, off);
  float s = 1.0f / fmaxf(sqrtf(ss), 1e-12f);
  float4 o = {v.x * s, v.y * s, v.z * s, v.w * s};
  *(float4*)(Rn + (size_t)row * 256 + lane * 4) = o;
}

// ---------------------------------------------------------------- sim = Rn @ Rn^T  (bf16 out)
__global__ void sim_kernel(const float* __restrict__ Rn, u16* __restrict__ sim16) {
  __shared__ float Rl[16 * 256];
  int i0 = blockIdx.x * 16;
  int t = threadIdx.x;
  #pragma unroll
  for (int i = 0; i < 4; i++) {
    int f = t + i * 256;
    *(float4*)&Rl[f * 4] = *(const float4*)(Rn + (size_t)i0 * 256 + f * 4);
  }
  __syncthreads();
  for (int jj = 0; jj < 2; jj++) {
    int j = jj * 256 + t;
    float acc[16];
    #pragma unroll
    for (int i = 0; i < 16; i++) acc[i] = 0.f;
    for (int c = 0; c < 64; c++) {
      float4 rv = *(const float4*)(Rn + (size_t)j * 256 + c * 4);
      #pragma unroll
      for (int i = 0; i < 16; i++) {
        float4 a = *(const float4*)&Rl[i * 256 + c * 4];
        acc[i] += a.x * rv.x + a.y * rv.y + a.z * rv.z + a.w * rv.w;
      }
    }
    #pragma unroll
    for (int i = 0; i < 16; i++) sim16[(size_t)(i0 + i) * 512 + j] = f2bf(acc[i]);
  }
}

// ---------------------------------------------------------------- GEMM: 256^2 8-phase
// R4 post-mortem: the 128^2 2-barrier structure sat at 770 TF (MfmaUtil 33%)
// — the guide-proven m97 ceiling (~900 TF). This is the m201 8-phase 256^2
// template in plain HIP: BM=BN=256, BK=64, 512 thr (8 waves, 2Mx4N), per-wave
// 128x64 out, LDS 128KB = A[2][256][64] + B[2][256][64] bf16 dbuf.
//
// st_16x32 swizzle (T2): chunk ^= ((row>>2)&1)<<1 (byte-bit5 ^= bit9), applied
// on BOTH global_load_lds source and ds_read (rule #21; LDS dest stays linear).
//
// Phase = {12 ds_read_b128 ; stage 1 half-tile (2 gload_lds) ; barrier ;
//          setprio(1) 16 MFMA setprio(0) ; [vmcnt(4) @ ph3/ph7] ; barrier}.
// Quadrant of phase p(0-3): mh=p>>1, nh=p&1. A-half S0=rows{0-63,128-191}
// read in ph0,1 ; S1 in ph2,3. B-half T0=rows{x*64..+31} read ph0,2 ; T1 ph1,3.
// Stage schedule (iter i, t0=2i buf0, t1=2i+1 buf1):
//   ph0: A-S1(t1)->buf1   (S1(buf1) last read prev ph6/7; barrier separates)
//   ph1: B-T1(t1)->buf1
//   ph2: A-S0(t0+2)->buf0 (S0(buf0) last read ph1)
//   ph3: B-T0(t0+2)->buf0 (T0(buf0) last read ph2) ; vmcnt(4): t1 data landed
//   ph4: A-S1(t0+2)->buf0 (S1(buf0) last read ph3)
//   ph5: B-T1(t0+2)->buf0
//   ph6: A-S0(t1+2)->buf1
//   ph7: B-T0(t1+2)->buf1 ; vmcnt(4): t0+2 data landed (ph6/7 stay in flight)
// vmcnt is never 0 in steady state; raw s_barrier (no compiler vmcnt(0) drain
// — that drain IS the m97 20% stall). FP K-order unchanged -> same absmax.
#define GEMM_PHASE(AB, BB, MH, NH, STAGE, WAITSTMT) {                         \
    bf16x8 af[4][2], bfv[2][2];                                               \
    _Pragma("unroll") for (int mi2 = 0; mi2 < 4; mi2++) {                     \
      int r = wm * 128 + ((MH) * 4 + mi2) * 16 + lr;                          \
      int sw = ((r >> 2) & 1) << 1;                                           \
      _Pragma("unroll") for (int ks = 0; ks < 2; ks++)                        \
        af[mi2][ks] = *(const bf16x8*)&(AB)[r * 64 + ((ks * 4 + qd) ^ sw) * 8]; \
    }                                                                         \
    _Pragma("unroll") for (int ni2 = 0; ni2 < 2; ni2++) {                     \
      int r = wn * 64 + ((NH) * 2 + ni2) * 16 + lr;                           \
      int sw = ((r >> 2) & 1) << 1;                                           \
      _Pragma("unroll") for (int ks = 0; ks < 2; ks++)                        \
        bfv[ni2][ks] = *(const bf16x8*)&(BB)[r * 64 + ((ks * 4 + qd) ^ sw) * 8]; \
    }                                                                         \
    STAGE;                                                                    \
    __builtin_amdgcn_sched_barrier(0);                                        \
    __builtin_amdgcn_s_barrier();                                             \
    __builtin_amdgcn_sched_barrier(0);                                        \
    __builtin_amdgcn_s_setprio(1);                                            \
    _Pragma("unroll") for (int mi2 = 0; mi2 < 4; mi2++)                       \
      _Pragma("unroll") for (int ni2 = 0; ni2 < 2; ni2++)                     \
        _Pragma("unroll") for (int ks = 0; ks < 2; ks++)                      \
          acc[(MH) * 4 + mi2][(NH) * 2 + ni2] =                               \
              __builtin_amdgcn_mfma_f32_16x16x32_bf16(                        \
                  af[mi2][ks], bfv[ni2][ks],                                  \
                  acc[(MH) * 4 + mi2][(NH) * 2 + ni2], 0, 0, 0);              \
    __builtin_amdgcn_s_setprio(0);                                            \
    WAITSTMT;                                                                 \
    __builtin_amdgcn_sched_barrier(0);                                        \
    __builtin_amdgcn_s_barrier();                                             \
  }

template <int MODE>
__global__ __launch_bounds__(512, 2)
void gemm_kernel(const u16* __restrict__ A,
                 const u16* __restrict__ B0, const u16* __restrict__ B1,
                 const u16* __restrict__ B2,
                 u16* __restrict__ q16, u16* __restrict__ k16, u16* __restrict__ v16,
                 float* __restrict__ outF) {
  __shared__ u16 smem[65536];        // 128 KB
  u16* const As0 = smem;
  u16* const As1 = smem + 16384;
  u16* const Bs0 = smem + 32768;
  u16* const Bs1 = smem + 49152;

  int tid = threadIdx.x;
  int wave = tid >> 6, lane = tid & 63;
  int wm = wave >> 2, wn = wave & 3;
  int lr = lane & 15, qd = lane >> 4;
  int mb = blockIdx.x * 256;
  int ny = blockIdx.y;

  const u16* Bmat;
  int nbase;
  if (MODE == 0) {
    int wsel = ny >> 2;
    Bmat = (wsel == 0 ? B0 : wsel == 1 ? B1 : B2);
    nbase = (ny & 3) * 256;
  } else {
    Bmat = B0;
    nbase = ny * 256;
  }
  const u16* Ag = A + (size_t)mb * 1024;
  const u16* Bg = Bmat + (size_t)nbase * 1024;

  // stage one A half-tile (128 rows: blocks {half,half+2} of 64) of K-tile
  // at gsrc into LDS tile dst. Linear LDS dest (wave-uniform base + lane*16);
  // swizzle applied on the global source chunk (involution, matches reads).
  auto stageA_ = [&](u16* dst, const u16* gsrc, int half) {
    int blk = ((wave < 4) ? 0 : 2) + half;
    int ws = wave & 3;
    #pragma unroll
    for (int jj = 0; jj < 2; jj++) {
      int rbase = blk * 64 + ws * 16 + jj * 8;
      int row = rbase + (lane >> 3);
      int c8 = (lane & 7) ^ (((row >> 2) & 1) << 1);
      async_cp16(gsrc + (size_t)row * 1024 + c8 * 8, dst + rbase * 64);
    }
  };
  // B half-tile: rows {st*64 + half*32 .. +31} for st=0..3
  auto stageB_ = [&](u16* dst, const u16* gsrc, int half) {
    int st = wave >> 1, sub = wave & 1;
    #pragma unroll
    for (int jj = 0; jj < 2; jj++) {
      int rbase = st * 64 + half * 32 + sub * 16 + jj * 8;
      int row = rbase + (lane >> 3);
      int c8 = (lane & 7) ^ (((row >> 2) & 1) << 1);
      async_cp16(gsrc + (size_t)row * 1024 + c8 * 8, dst + rbase * 64);
    }
  };

  f32x4 acc[8][4];
  #pragma unroll
  for (int i = 0; i < 8; i++)
    #pragma unroll
    for (int j = 0; j < 4; j++) acc[i][j] = f32x4{0.f, 0.f, 0.f, 0.f};

  // prologue: full K-tile 0 + halves S0/T0 of K-tile 1 (12 loads/thread)
  stageA_(As0, Ag, 0);
  stageB_(Bs0, Bg, 0);
  stageA_(As0, Ag, 1);
  stageB_(Bs0, Bg, 1);
  stageA_(As1, Ag + 64, 0);
  stageB_(Bs1, Bg + 64, 0);
  asm volatile("s_waitcnt vmcnt(4)" ::: "memory");   // K-tile 0 landed
  __builtin_amdgcn_sched_barrier(0);
  __builtin_amdgcn_s_barrier();

  #pragma unroll 1
  for (int i = 0; i < 8; i++) {
    int t1 = 2 * i + 1;
    bool more = (i < 7);
    const u16* Ag1 = Ag + t1 * 64;
    const u16* Bg1 = Bg + t1 * 64;
    const u16* Ag2 = Ag + (t1 + 1) * 64;
    const u16* Bg2 = Bg + (t1 + 1) * 64;
    const u16* Ag3 = Ag + (t1 + 2) * 64;
    const u16* Bg3 = Bg + (t1 + 2) * 64;

    GEMM_PHASE(As0, Bs0, 0, 0, { stageA_(As1, Ag1, 1); }, {});
    GEMM_PHASE(As0, Bs0, 0, 1, { stageB_(Bs1, Bg1, 1); }, {});
    GEMM_PHASE(As0, Bs0, 1, 0, { if (more) stageA_(As0, Ag2, 0); }, {});
    GEMM_PHASE(As0, Bs0, 1, 1, { if (more) stageB_(Bs0, Bg2, 0); },
               { if (more) asm volatile("s_waitcnt vmcnt(4)" ::: "memory");
                 else      asm volatile("s_waitcnt vmcnt(0)" ::: "memory"); });
    GEMM_PHASE(As1, Bs1, 0, 0, { if (more) stageA_(As0, Ag2, 1); }, {});
    GEMM_PHASE(As1, Bs1, 0, 1, { if (more) stageB_(Bs0, Bg2, 1); }, {});
    GEMM_PHASE(As1, Bs1, 1, 0, { if (more) stageA_(As1, Ag3, 0); }, {});
    GEMM_PHASE(As1, Bs1, 1, 1, { if (more) stageB_(Bs1, Bg3, 0); },
               { if (more) asm volatile("s_waitcnt vmcnt(4)" ::: "memory"); });
  }

  if (MODE == 0) {
    int wsel = ny >> 2;
    u16* dst = (wsel == 0 ? q16 : wsel == 1 ? k16 : v16);
    // Q gets 1/sqrt(D)*log2(e): scores land in the exp2 domain.
    float scl = (wsel == 0) ? QK_SCALE * LOG2E : 1.0f;
    #pragma unroll
    for (int mi = 0; mi < 8; mi++) {
      int m = mb + wm * 128 + mi * 16 + qd * 4;
      int b = m >> 9, kk = m & 511;
      #pragma unroll
      for (int ni = 0; ni < 4; ni++) {
        int n = nbase + wn * 64 + ni * 16 + lr;
        int h = n >> 6, d = n & 63;
        u16* p = dst + ((size_t)(b * 16 + h) * 512 + kk) * 64 + d;
        #pragma unroll
        for (int r = 0; r < 4; r++) p[(size_t)r * 64] = f2bf(acc[mi][ni][r] * scl);
      }
    }
  } else {
    #pragma unroll
    for (int mi = 0; mi < 8; mi++) {
      int m = mb + wm * 128 + mi * 16 + qd * 4;
      #pragma unroll
      for (int ni = 0; ni < 4; ni++) {
        int n = nbase + wn * 64 + ni * 16 + lr;
        #pragma unroll
        for (int r = 0; r < 4; r++) outF[(size_t)(m + r) * 1024 + n] = acc[mi][ni][r];
      }
    }
  }
}

// ---------------------------------------------------------------- V transpose
__global__ void vtrans_kernel(const u16* __restrict__ v16, u16* __restrict__ vt16) {
  __shared__ u16 tile[64 * 72];
  int kt = blockIdx.x;
  int bh = blockIdx.y;
  int t = threadIdx.x;
  const u16* src = v16 + ((size_t)bh * 512 + kt * 64) * 64;
  #pragma unroll
  for (int j = 0; j < 2; j++) {
    int linear = j * 2048 + t * 8;
    int kr = linear >> 6, d0 = linear & 63;
    bf16x8 vv = *(const bf16x8*)(src + (size_t)kr * 64 + d0);
    #pragma unroll
    for (int e = 0; e < 8; e++) tile[kr * 72 + d0 + e] = (u16)vv[e];
  }
  __syncthreads();
  #pragma unroll
  for (int j = 0; j < 2; j++) {
    int linear = j * 2048 + t * 8;
    int dr = linear >> 6, k0 = linear & 63;
    bf16x8 ov;
    #pragma unroll
    for (int e = 0; e < 8; e++) ov[e] = (short)tile[(k0 + e) * 72 + dr];
    *(bf16x8*)(vt16 + ((size_t)bh * 64 + dr) * 512 + kt * 64 + k0) = ov;
  }
}

// ---------------------------------------------------------------- fused attention v6b
// (unchanged from R4 — verified: T12 in-register softmax via swapped 32x32
// QK^T, permlane32_swap stats + P fragments, counted-vmcnt K/V prefetch)
__global__ __launch_bounds__(256, 3)
void attn_kernel(const u16* __restrict__ q16, const u16* __restrict__ k16,
                 const u16* __restrict__ vt16, const u16* __restrict__ sim16,
                 const float* __restrict__ wsim, u16* __restrict__ attn16) {
  __shared__ u16 smem[16384];   // 32 KB: K dbuf [2][64*64] + Vt dbuf [2][64*64]

  int id = blockIdx.x;
  int xcd = id & 7;
  int j = id >> 3;
  int qt = j & 3;
  int bh = xcd * 64 + (j >> 2);
  int b = bh >> 4, h = bh & 15;

  int tid = threadIdx.x;
  int wave = tid >> 6, lane = tid & 63;
  int l31 = lane & 31, hi = lane >> 5;
  int qb = qt * 128 + wave * 32;        // this wave's 32 q rows

  const u16* qp = q16 + ((size_t)bh * 512 + qb + l31) * 64 + hi * 8;
  bf16x8 aq[4];
  #pragma unroll
  for (int ds = 0; ds < 4; ds++) aq[ds] = *(const bf16x8*)(qp + ds * 16);

  float ws = wsim[h] * LOG2E;           // bias in exp2 domain

  f32x16 o[2];
  #pragma unroll
  for (int dt = 0; dt < 2; dt++)
    #pragma unroll
    for (int r = 0; r < 16; r++) o[dt][r] = 0.f;
  float m_run = -1e30f, l_run = 0.f;

  const u16* kbase = k16 + (size_t)bh * 512 * 64;
  const u16* vbase = vt16 + (size_t)bh * 64 * 512;

  auto stage = [&](int nb, int ck) {
    int k0 = ck * 64;
    u16* kd = smem + nb * 4096;
    u16* vd = smem + 8192 + nb * 4096;
    #pragma unroll
    for (int it = 0; it < 2; it++) {
      int idx = it * 256 + wave * 64 + lane;
      int r = idx >> 3, c8 = idx & 7;
      async_cp16(kbase + (size_t)(k0 + r) * 64 + ((c8 ^ (r & 7)) << 3),
                 kd + (it * 256 + wave * 64) * 8);
    }
    #pragma unroll
    for (int it = 0; it < 2; it++) {
      int idx = it * 256 + wave * 64 + lane;
      int dr = idx >> 3, c8 = idx & 7;
      async_cp16(vbase + (size_t)dr * 512 + k0 + ((c8 ^ (dr & 7)) << 3),
                 vd + (it * 256 + wave * 64) * 8);
    }
  };

  stage(0, 0);
  __syncthreads();

  int cur = 0;
  for (int ck = 0; ck < 8; ck++) {
    int k0 = ck * 64;

    uint2 braw[8];
    #pragma unroll
    for (int kb = 0; kb < 2; kb++)
      #pragma unroll
      for (int g = 0; g < 4; g++)
        braw[kb * 4 + g] = *(const uint2*)(sim16 + (size_t)(qb + l31) * 512 +
                                           k0 + kb * 32 + g * 8 + hi * 4);
    __builtin_amdgcn_sched_barrier(0);
    if (ck < 7) stage(cur ^ 1, ck + 1);

    const u16* Kc = smem + cur * 4096;
    const u16* Vc = smem + 8192 + cur * 4096;

    f32x16 s[2];
    __builtin_amdgcn_s_setprio(1);
    #pragma unroll
    for (int kb = 0; kb < 2; kb++) {
      f32x16 acc;
      #pragma unroll
      for (int r = 0; r < 16; r++) {
        u32 w = ((r >> 1) & 1) ? braw[kb * 4 + (r >> 2)].y
                               : braw[kb * 4 + (r >> 2)].x;
        acc[r] = ws * __uint_as_float((r & 1) ? (w & 0xFFFF0000u) : (w << 16));
      }
      int koff = kb * 32 + l31;
      #pragma unroll
      for (int ds = 0; ds < 4; ds++) {
        bf16x8 kf = *(const bf16x8*)&Kc[koff * 64 + (((ds * 2 + hi) ^ (koff & 7)) << 3)];
        acc = __builtin_amdgcn_mfma_f32_32x32x16_bf16(kf, aq[ds], acc, 0, 0, 0);
      }
      s[kb] = acc;
    }
    __builtin_amdgcn_s_setprio(0);

    float v8[8];
    #pragma unroll
    for (int i = 0; i < 8; i++)
      v8[i] = fmaxf(fmaxf(s[0][i], s[0][i + 8]), fmaxf(s[1][i], s[1][i + 8]));
    float m_in = fmaxf(fmaxf(fmaxf(v8[0], v8[1]), fmaxf(v8[2], v8[3])),
                       fmaxf(fmaxf(v8[4], v8[5]), fmaxf(v8[6], v8[7])));
    u32 xa = __float_as_uint(m_in), xb = __float_as_uint(m_in);
    plswap(xa, xb);
    float m_tile = fmaxf(__uint_as_float(xa), __uint_as_float(xb));
    float mnew = fmaxf(m_run, m_tile);
    float alpha = fexp2(m_run - mnew);
    m_run = mnew;

    float c0 = 0.f, c1 = 0.f, c2 = 0.f, c3 = 0.f;
    #pragma unroll
    for (int kb = 0; kb < 2; kb++)
      #pragma unroll
      for (int i = 0; i < 16; i++) {
        float e = fexp2(s[kb][i] - mnew);
        s[kb][i] = e;
        if ((i & 3) == 0) c0 += e; else if ((i & 3) == 1) c1 += e;
        else if ((i & 3) == 2) c2 += e; else c3 += e;
      }
    float cs = (c0 + c1) + (c2 + c3);
    u32 ya = __float_as_uint(cs), yb = __float_as_uint(cs);
    plswap(ya, yb);
    float cs_tot = __uint_as_float(ya) + __uint_as_float(yb);
    l_run = l_run * alpha + cs_tot;

    #pragma unroll
    for (int dt = 0; dt < 2; dt++) o[dt] *= alpha;

    __builtin_amdgcn_s_setprio(1);
    #pragma unroll
    for (int ks = 0; ks < 4; ks++) {
      int kb = ks >> 1, j4 = (ks & 1) * 8;
      u32 a0 = pkbf(s[kb][j4 + 0], s[kb][j4 + 1]);
      u32 a1 = pkbf(s[kb][j4 + 2], s[kb][j4 + 3]);
      u32 b0 = pkbf(s[kb][j4 + 4], s[kb][j4 + 5]);
      u32 b1 = pkbf(s[kb][j4 + 6], s[kb][j4 + 7]);
      plswap(a0, b0);
      plswap(a1, b1);
      union { u32 w[4]; bf16x8 v; } U;
      U.w[0] = a0; U.w[1] = a1; U.w[2] = b0; U.w[3] = b1;
      #pragma unroll
      for (int dt = 0; dt < 2; dt++) {
        int dr = dt * 32 + l31;
        bf16x8 vf = *(const bf16x8*)&Vc[dr * 64 + (((ks * 2 + hi) ^ (dr & 7)) << 3)];
        o[dt] = __builtin_amdgcn_mfma_f32_32x32x16_bf16(vf, U.v, o[dt], 0, 0, 0);
      }
    }
    __builtin_amdgcn_s_setprio(0);

    __syncthreads();
    cur ^= 1;
  }

  float linv = 1.0f / l_run;
  u16* Ow = smem + wave * 2304;   // [32 q][72 d] u16
  #pragma unroll
  for (int dt = 0; dt < 2; dt++)
    #pragma unroll
    for (int g = 0; g < 4; g++) {
      u32 w0 = pkbf(o[dt][4 * g + 0] * linv, o[dt][4 * g + 1] * linv);
      u32 w1 = pkbf(o[dt][4 * g + 2] * linv, o[dt][4 * g + 3] * linv);
      uint2 pr; pr.x = w0; pr.y = w1;
      *(uint2*)&Ow[l31 * 72 + dt * 32 + g * 8 + hi * 4] = pr;
    }
  #pragma unroll
  for (int i = 0; i < 4; i++) {
    int idx = i * 64 + lane;
    int row = idx >> 3, seg = idx & 7;
    bf16x8 val = *(const bf16x8*)&Ow[row * 72 + seg * 8];
    *(bf16x8*)(attn16 + ((size_t)b * 512 + qb + row) * 1024 + h * 64 + seg * 8) = val;
  }
}

// ---------------------------------------------------------------- launch
extern "C" void kernel_launch(void* const* d_in, const int* in_sizes, int n_in,
                              void* d_out, int out_size, void* d_ws, size_t ws_size,
                              hipStream_t stream) {
  const float* hR  = (const float*)d_in[0];
  const float* R   = (const float*)d_in[1];
  const float* Wq  = (const float*)d_in[2];
  const float* Wk  = (const float*)d_in[3];
  const float* Wv  = (const float*)d_in[4];
  const float* Wo  = (const float*)d_in[5];
  const float* wsm = (const float*)d_in[6];
  float* out = (float*)d_out;

  const size_t NE = 16777216;   // 16384 x 1024
  u16* ws16   = (u16*)d_ws;
  u16* hR16   = ws16;
  u16* attn16 = ws16;           // reuses hR16 (consumed by QKV GEMM)
  u16* q16    = ws16 + NE;
  u16* k16    = ws16 + 2 * NE;
  u16* v16    = ws16 + 3 * NE;
  u16* vt16   = ws16 + 4 * NE;
  u16* Wq16   = ws16 + 5 * NE;
  u16* Wk16   = Wq16 + 1048576;
  u16* Wv16   = Wk16 + 1048576;
  u16* Wo16   = Wv16 + 1048576;
  u16* sim16  = Wo16 + 1048576;              // 512*512 bf16
  float* Rn   = (float*)(sim16 + 262144);    // 512*256 fp32

  convert_kernel<<<20480, 256, 0, stream>>>(hR, Wq, Wk, Wv, Wo,
                                            hR16, Wq16, Wk16, Wv16, Wo16);
  rnorm_kernel<<<512, 64, 0, stream>>>(R, Rn);
  sim_kernel<<<32, 256, 0, stream>>>(Rn, sim16);
  gemm_kernel<0><<<dim3(64, 12), 512, 0, stream>>>(hR16, Wq16, Wk16, Wv16,
                                                   q16, k16, v16, nullptr);
  vtrans_kernel<<<dim3(8, 512), 256, 0, stream>>>(v16, vt16);
  attn_kernel<<<2048, 256, 0, stream>>>(q16, k16, vt16, sim16, wsm, attn16);
  gemm_kernel<1><<<dim3(64, 4), 512, 0, stream>>>(attn16, Wo16, nullptr, nullptr,
                                                  nullptr, nullptr, nullptr, out);
}

// Round 6
// 432.689 us; speedup vs baseline: 1.0721x; 1.0721x over previous
//
#include <hip/hip_runtime.h>

#define SEQK 512
#define NH 16
#define HD 64
#define RD 1024
#define BBATCH 32
#define QK_SCALE 0.125f        // 1/sqrt(64)
#define LOG2E 1.4426950408889634f

typedef unsigned short u16;
typedef unsigned int u32;
using bf16x8 = __attribute__((ext_vector_type(8))) short;
using f32x4  = __attribute__((ext_vector_type(4))) float;
using f32x16 = __attribute__((ext_vector_type(16))) float;

__device__ __forceinline__ u16 f2bf(float f) {
  unsigned u = __float_as_uint(f);
  u += 0x7FFFu + ((u >> 16) & 1u);   // round-to-nearest-even
  return (u16)(u >> 16);
}
__device__ __forceinline__ float bf2f(u16 v) {
  return __uint_as_float(((unsigned)v) << 16);
}
// 2^x in one VALU op (inputs are pre-scaled by LOG2E upstream)
__device__ __forceinline__ float fexp2(float x) {
  float r;
  asm("v_exp_f32 %0, %1" : "=v"(r) : "v"(x));
  return r;
}
// packed f32x2 -> bf16x2 (RNE), lo in [15:0], hi in [31:16]  (m240 recipe)
__device__ __forceinline__ u32 pkbf(float lo, float hi) {
  u32 r;
  asm("v_cvt_pk_bf16_f32 %0, %1, %2" : "=v"(r) : "v"(lo), "v"(hi));
  return r;
}
// swap a's upper 32 lanes with b's lower 32 lanes (gfx950 permlane32_swap)
__device__ __forceinline__ void plswap(u32& a, u32& b) {
#if __has_builtin(__builtin_amdgcn_permlane32_swap)
  typedef int v2i __attribute__((ext_vector_type(2)));
  v2i r = __builtin_amdgcn_permlane32_swap((int)a, (int)b, false, false);
  a = (u32)r[0]; b = (u32)r[1];
#else
  asm volatile("v_permlane32_swap_b32 %0, %1" : "+v"(a), "+v"(b));
#endif
}

__device__ __forceinline__ void async_cp16(const void* g, void* l) {
  __builtin_amdgcn_global_load_lds(
      (__attribute__((address_space(1))) void*)(void*)g,
      (__attribute__((address_space(3))) void*)l,
      16, 0, 0);
}

// ---------------------------------------------------------------- convert
__global__ void convert_kernel(const float* __restrict__ hR,
                               const float* __restrict__ Wq, const float* __restrict__ Wk,
                               const float* __restrict__ Wv, const float* __restrict__ Wo,
                               u16* __restrict__ hR16,
                               u16* __restrict__ Wq16, u16* __restrict__ Wk16,
                               u16* __restrict__ Wv16, u16* __restrict__ Wo16) {
  size_t i4 = (size_t)blockIdx.x * blockDim.x + threadIdx.x;
  size_t e = i4 * 4;
  const float* src; u16* dst; size_t off;
  if (e < 16777216u) { src = hR; dst = hR16; off = e; }
  else {
    size_t r = e - 16777216u;
    int w = (int)(r >> 20);
    off = r & 1048575u;
    src = (w == 0 ? Wq : w == 1 ? Wk : w == 2 ? Wv : Wo);
    dst = (w == 0 ? Wq16 : w == 1 ? Wk16 : w == 2 ? Wv16 : Wo16);
  }
  float4 v = *(const float4*)(src + off);
  ushort4 o;
  o.x = f2bf(v.x); o.y = f2bf(v.y); o.z = f2bf(v.z); o.w = f2bf(v.w);
  *(ushort4*)(dst + off) = o;
}

// ---------------------------------------------------------------- R normalize
__global__ void rnorm_kernel(const float* __restrict__ R, float* __restrict__ Rn) {
  int row = blockIdx.x;
  int lane = threadIdx.x;
  float4 v = *(const float4*)(R + (size_t)row * 256 + lane * 4);
  float ss = v.x * v.x + v.y * v.y + v.z * v.z + v.w * v.w;
  for (int off = 32; off; off >>= 1) ss += __shfl_xor(ss, off);
  float s = 1.0f / fmaxf(sqrtf(ss), 1e-12f);
  float4 o = {v.x * s, v.y * s, v.z * s, v.w * s};
  *(float4*)(Rn + (size_t)row * 256 + lane * 4) = o;
}

// ---------------------------------------------------------------- sim = Rn @ Rn^T  (bf16 out)
__global__ void sim_kernel(const float* __restrict__ Rn, u16* __restrict__ sim16) {
  __shared__ float Rl[16 * 256];
  int i0 = blockIdx.x * 16;
  int t = threadIdx.x;
  #pragma unroll
  for (int i = 0; i < 4; i++) {
    int f = t + i * 256;
    *(float4*)&Rl[f * 4] = *(const float4*)(Rn + (size_t)i0 * 256 + f * 4);
  }
  __syncthreads();
  for (int jj = 0; jj < 2; jj++) {
    int j = jj * 256 + t;
    float acc[16];
    #pragma unroll
    for (int i = 0; i < 16; i++) acc[i] = 0.f;
    for (int c = 0; c < 64; c++) {
      float4 rv = *(const float4*)(Rn + (size_t)j * 256 + c * 4);
      #pragma unroll
      for (int i = 0; i < 16; i++) {
        float4 a = *(const float4*)&Rl[i * 256 + c * 4];
        acc[i] += a.x * rv.x + a.y * rv.y + a.z * rv.z + a.w * rv.w;
      }
    }
    #pragma unroll
    for (int i = 0; i < 16; i++) sim16[(size_t)(i0 + i) * 512 + j] = f2bf(acc[i]);
  }
}

// ---------------------------------------------------------------- GEMM: 256^2 8-phase
// R5 post-mortem: structure correct but swizzle was 1-bit -> lanes 0-7 hit
// only 2 of 8 chunk slots -> 4-way ds_read conflict (18.9M). Conflict model:
// ds_read_b128 services 8 lanes/cycle (8x16B = 32 banks); conflict-free iff
// each consecutive-8-lane group covers all 8 slots. At 128B row stride the
// row index contributes NOTHING to bank bits, so the chunk swizzle must be
// the full 3-bit XOR: slot = chunk ^ (row&7). (The old 128^2 kernel was
// clean because 64B rows put row-bit0 in bank-bit6 + 2-bit XOR; the attn
// kernel already uses ^(row&7).) Applied on BOTH global_load_lds source and
// ds_read (rule #21; LDS dest stays linear).
//
// Phase = {12 ds_read_b128 ; stage 1 half-tile (2 gload_lds) ; barrier ;
//          setprio(1) 16 MFMA setprio(0) ; [vmcnt(4) @ ph3/ph7] ; barrier}.
// Stage schedule (iter i, t0=2i buf0, t1=2i+1 buf1):
//   ph0: A-S1(t1)->buf1   ph1: B-T1(t1)->buf1
//   ph2: A-S0(t0+2)->buf0 ph3: B-T0(t0+2)->buf0 ; vmcnt(4): t1 landed
//   ph4: A-S1(t0+2)->buf0 ph5: B-T1(t0+2)->buf0
//   ph6: A-S0(t1+2)->buf1 ph7: B-T0(t1+2)->buf1 ; vmcnt(4): t0+2 landed
// vmcnt never 0 in steady state; raw s_barrier (no compiler vmcnt(0) drain).
#define GEMM_PHASE(AB, BB, MH, NH, STAGE, WAITSTMT) {                         \
    bf16x8 af[4][2], bfv[2][2];                                               \
    _Pragma("unroll") for (int mi2 = 0; mi2 < 4; mi2++) {                     \
      int r = wm * 128 + ((MH) * 4 + mi2) * 16 + lr;                          \
      int sw = r & 7;                                                         \
      _Pragma("unroll") for (int ks = 0; ks < 2; ks++)                        \
        af[mi2][ks] = *(const bf16x8*)&(AB)[r * 64 + ((ks * 4 + qd) ^ sw) * 8]; \
    }                                                                         \
    _Pragma("unroll") for (int ni2 = 0; ni2 < 2; ni2++) {                     \
      int r = wn * 64 + ((NH) * 2 + ni2) * 16 + lr;                           \
      int sw = r & 7;                                                         \
      _Pragma("unroll") for (int ks = 0; ks < 2; ks++)                        \
        bfv[ni2][ks] = *(const bf16x8*)&(BB)[r * 64 + ((ks * 4 + qd) ^ sw) * 8]; \
    }                                                                         \
    STAGE;                                                                    \
    __builtin_amdgcn_sched_barrier(0);                                        \
    __builtin_amdgcn_s_barrier();                                             \
    __builtin_amdgcn_sched_barrier(0);                                        \
    __builtin_amdgcn_s_setprio(1);                                            \
    _Pragma("unroll") for (int mi2 = 0; mi2 < 4; mi2++)                       \
      _Pragma("unroll") for (int ni2 = 0; ni2 < 2; ni2++)                     \
        _Pragma("unroll") for (int ks = 0; ks < 2; ks++)                      \
          acc[(MH) * 4 + mi2][(NH) * 2 + ni2] =                               \
              __builtin_amdgcn_mfma_f32_16x16x32_bf16(                        \
                  af[mi2][ks], bfv[ni2][ks],                                  \
                  acc[(MH) * 4 + mi2][(NH) * 2 + ni2], 0, 0, 0);              \
    __builtin_amdgcn_s_setprio(0);                                            \
    WAITSTMT;                                                                 \
    __builtin_amdgcn_sched_barrier(0);                                        \
    __builtin_amdgcn_s_barrier();                                             \
  }

template <int MODE>
__global__ __launch_bounds__(512, 2)
void gemm_kernel(const u16* __restrict__ A,
                 const u16* __restrict__ B0, const u16* __restrict__ B1,
                 const u16* __restrict__ B2,
                 u16* __restrict__ q16, u16* __restrict__ k16, u16* __restrict__ v16,
                 float* __restrict__ outF) {
  __shared__ u16 smem[65536];        // 128 KB
  u16* const As0 = smem;
  u16* const As1 = smem + 16384;
  u16* const Bs0 = smem + 32768;
  u16* const Bs1 = smem + 49152;

  int tid = threadIdx.x;
  int wave = tid >> 6, lane = tid & 63;
  int wm = wave >> 2, wn = wave & 3;
  int lr = lane & 15, qd = lane >> 4;
  int mb = blockIdx.x * 256;
  int ny = blockIdx.y;

  const u16* Bmat;
  int nbase;
  if (MODE == 0) {
    int wsel = ny >> 2;
    Bmat = (wsel == 0 ? B0 : wsel == 1 ? B1 : B2);
    nbase = (ny & 3) * 256;
  } else {
    Bmat = B0;
    nbase = ny * 256;
  }
  const u16* Ag = A + (size_t)mb * 1024;
  const u16* Bg = Bmat + (size_t)nbase * 1024;

  // stage one A half-tile (128 rows: blocks {half,half+2} of 64) of K-tile
  // at gsrc into LDS tile dst. Linear LDS dest (wave-uniform base + lane*16);
  // 3-bit swizzle on the global source chunk (involution, matches reads).
  auto stageA_ = [&](u16* dst, const u16* gsrc, int half) {
    int blk = ((wave < 4) ? 0 : 2) + half;
    int ws = wave & 3;
    #pragma unroll
    for (int jj = 0; jj < 2; jj++) {
      int rbase = blk * 64 + ws * 16 + jj * 8;
      int row = rbase + (lane >> 3);
      int c8 = (lane & 7) ^ (row & 7);
      async_cp16(gsrc + (size_t)row * 1024 + c8 * 8, dst + rbase * 64);
    }
  };
  // B half-tile: rows {st*64 + half*32 .. +31} for st=0..3
  auto stageB_ = [&](u16* dst, const u16* gsrc, int half) {
    int st = wave >> 1, sub = wave & 1;
    #pragma unroll
    for (int jj = 0; jj < 2; jj++) {
      int rbase = st * 64 + half * 32 + sub * 16 + jj * 8;
      int row = rbase + (lane >> 3);
      int c8 = (lane & 7) ^ (row & 7);
      async_cp16(gsrc + (size_t)row * 1024 + c8 * 8, dst + rbase * 64);
    }
  };

  f32x4 acc[8][4];
  #pragma unroll
  for (int i = 0; i < 8; i++)
    #pragma unroll
    for (int j = 0; j < 4; j++) acc[i][j] = f32x4{0.f, 0.f, 0.f, 0.f};

  // prologue: full K-tile 0 + halves S0/T0 of K-tile 1 (12 loads/thread)
  stageA_(As0, Ag, 0);
  stageB_(Bs0, Bg, 0);
  stageA_(As0, Ag, 1);
  stageB_(Bs0, Bg, 1);
  stageA_(As1, Ag + 64, 0);
  stageB_(Bs1, Bg + 64, 0);
  asm volatile("s_waitcnt vmcnt(4)" ::: "memory");   // K-tile 0 landed
  __builtin_amdgcn_sched_barrier(0);
  __builtin_amdgcn_s_barrier();

  #pragma unroll 1
  for (int i = 0; i < 8; i++) {
    int t1 = 2 * i + 1;
    bool more = (i < 7);
    const u16* Ag1 = Ag + t1 * 64;
    const u16* Bg1 = Bg + t1 * 64;
    const u16* Ag2 = Ag + (t1 + 1) * 64;
    const u16* Bg2 = Bg + (t1 + 1) * 64;
    const u16* Ag3 = Ag + (t1 + 2) * 64;
    const u16* Bg3 = Bg + (t1 + 2) * 64;

    GEMM_PHASE(As0, Bs0, 0, 0, { stageA_(As1, Ag1, 1); }, {});
    GEMM_PHASE(As0, Bs0, 0, 1, { stageB_(Bs1, Bg1, 1); }, {});
    GEMM_PHASE(As0, Bs0, 1, 0, { if (more) stageA_(As0, Ag2, 0); }, {});
    GEMM_PHASE(As0, Bs0, 1, 1, { if (more) stageB_(Bs0, Bg2, 0); },
               { if (more) asm volatile("s_waitcnt vmcnt(4)" ::: "memory");
                 else      asm volatile("s_waitcnt vmcnt(0)" ::: "memory"); });
    GEMM_PHASE(As1, Bs1, 0, 0, { if (more) stageA_(As0, Ag2, 1); }, {});
    GEMM_PHASE(As1, Bs1, 0, 1, { if (more) stageB_(Bs0, Bg2, 1); }, {});
    GEMM_PHASE(As1, Bs1, 1, 0, { if (more) stageA_(As1, Ag3, 0); }, {});
    GEMM_PHASE(As1, Bs1, 1, 1, { if (more) stageB_(Bs1, Bg3, 0); },
               { if (more) asm volatile("s_waitcnt vmcnt(4)" ::: "memory"); });
  }

  if (MODE == 0) {
    int wsel = ny >> 2;
    u16* dst = (wsel == 0 ? q16 : wsel == 1 ? k16 : v16);
    // Q gets 1/sqrt(D)*log2(e): scores land in the exp2 domain.
    float scl = (wsel == 0) ? QK_SCALE * LOG2E : 1.0f;
    #pragma unroll
    for (int mi = 0; mi < 8; mi++) {
      int m = mb + wm * 128 + mi * 16 + qd * 4;
      int b = m >> 9, kk = m & 511;
      #pragma unroll
      for (int ni = 0; ni < 4; ni++) {
        int n = nbase + wn * 64 + ni * 16 + lr;
        int h = n >> 6, d = n & 63;
        u16* p = dst + ((size_t)(b * 16 + h) * 512 + kk) * 64 + d;
        #pragma unroll
        for (int r = 0; r < 4; r++) p[(size_t)r * 64] = f2bf(acc[mi][ni][r] * scl);
      }
    }
  } else {
    #pragma unroll
    for (int mi = 0; mi < 8; mi++) {
      int m = mb + wm * 128 + mi * 16 + qd * 4;
      #pragma unroll
      for (int ni = 0; ni < 4; ni++) {
        int n = nbase + wn * 64 + ni * 16 + lr;
        #pragma unroll
        for (int r = 0; r < 4; r++) outF[(size_t)(m + r) * 1024 + n] = acc[mi][ni][r];
      }
    }
  }
}

// ---------------------------------------------------------------- V transpose
__global__ void vtrans_kernel(const u16* __restrict__ v16, u16* __restrict__ vt16) {
  __shared__ u16 tile[64 * 72];
  int kt = blockIdx.x;
  int bh = blockIdx.y;
  int t = threadIdx.x;
  const u16* src = v16 + ((size_t)bh * 512 + kt * 64) * 64;
  #pragma unroll
  for (int j = 0; j < 2; j++) {
    int linear = j * 2048 + t * 8;
    int kr = linear >> 6, d0 = linear & 63;
    bf16x8 vv = *(const bf16x8*)(src + (size_t)kr * 64 + d0);
    #pragma unroll
    for (int e = 0; e < 8; e++) tile[kr * 72 + d0 + e] = (u16)vv[e];
  }
  __syncthreads();
  #pragma unroll
  for (int j = 0; j < 2; j++) {
    int linear = j * 2048 + t * 8;
    int dr = linear >> 6, k0 = linear & 63;
    bf16x8 ov;
    #pragma unroll
    for (int e = 0; e < 8; e++) ov[e] = (short)tile[(k0 + e) * 72 + dr];
    *(bf16x8*)(vt16 + ((size_t)bh * 64 + dr) * 512 + kt * 64 + k0) = ov;
  }
}

// ---------------------------------------------------------------- fused attention v6b
// (unchanged — verified: T12 in-register softmax via swapped 32x32 QK^T,
// permlane32_swap stats + P fragments, counted-vmcnt K/V prefetch)
__global__ __launch_bounds__(256, 3)
void attn_kernel(const u16* __restrict__ q16, const u16* __restrict__ k16,
                 const u16* __restrict__ vt16, const u16* __restrict__ sim16,
                 const float* __restrict__ wsim, u16* __restrict__ attn16) {
  __shared__ u16 smem[16384];   // 32 KB: K dbuf [2][64*64] + Vt dbuf [2][64*64]

  int id = blockIdx.x;
  int xcd = id & 7;
  int j = id >> 3;
  int qt = j & 3;
  int bh = xcd * 64 + (j >> 2);
  int b = bh >> 4, h = bh & 15;

  int tid = threadIdx.x;
  int wave = tid >> 6, lane = tid & 63;
  int l31 = lane & 31, hi = lane >> 5;
  int qb = qt * 128 + wave * 32;        // this wave's 32 q rows

  const u16* qp = q16 + ((size_t)bh * 512 + qb + l31) * 64 + hi * 8;
  bf16x8 aq[4];
  #pragma unroll
  for (int ds = 0; ds < 4; ds++) aq[ds] = *(const bf16x8*)(qp + ds * 16);

  float ws = wsim[h] * LOG2E;           // bias in exp2 domain

  f32x16 o[2];
  #pragma unroll
  for (int dt = 0; dt < 2; dt++)
    #pragma unroll
    for (int r = 0; r < 16; r++) o[dt][r] = 0.f;
  float m_run = -1e30f, l_run = 0.f;

  const u16* kbase = k16 + (size_t)bh * 512 * 64;
  const u16* vbase = vt16 + (size_t)bh * 64 * 512;

  auto stage = [&](int nb, int ck) {
    int k0 = ck * 64;
    u16* kd = smem + nb * 4096;
    u16* vd = smem + 8192 + nb * 4096;
    #pragma unroll
    for (int it = 0; it < 2; it++) {
      int idx = it * 256 + wave * 64 + lane;
      int r = idx >> 3, c8 = idx & 7;
      async_cp16(kbase + (size_t)(k0 + r) * 64 + ((c8 ^ (r & 7)) << 3),
                 kd + (it * 256 + wave * 64) * 8);
    }
    #pragma unroll
    for (int it = 0; it < 2; it++) {
      int idx = it * 256 + wave * 64 + lane;
      int dr = idx >> 3, c8 = idx & 7;
      async_cp16(vbase + (size_t)dr * 512 + k0 + ((c8 ^ (dr & 7)) << 3),
                 vd + (it * 256 + wave * 64) * 8);
    }
  };

  stage(0, 0);
  __syncthreads();

  int cur = 0;
  for (int ck = 0; ck < 8; ck++) {
    int k0 = ck * 64;

    uint2 braw[8];
    #pragma unroll
    for (int kb = 0; kb < 2; kb++)
      #pragma unroll
      for (int g = 0; g < 4; g++)
        braw[kb * 4 + g] = *(const uint2*)(sim16 + (size_t)(qb + l31) * 512 +
                                           k0 + kb * 32 + g * 8 + hi * 4);
    __builtin_amdgcn_sched_barrier(0);
    if (ck < 7) stage(cur ^ 1, ck + 1);

    const u16* Kc = smem + cur * 4096;
    const u16* Vc = smem + 8192 + cur * 4096;

    f32x16 s[2];
    __builtin_amdgcn_s_setprio(1);
    #pragma unroll
    for (int kb = 0; kb < 2; kb++) {
      f32x16 acc;
      #pragma unroll
      for (int r = 0; r < 16; r++) {
        u32 w = ((r >> 1) & 1) ? braw[kb * 4 + (r >> 2)].y
                               : braw[kb * 4 + (r >> 2)].x;
        acc[r] = ws * __uint_as_float((r & 1) ? (w & 0xFFFF0000u) : (w << 16));
      }
      int koff = kb * 32 + l31;
      #pragma unroll
      for (int ds = 0; ds < 4; ds++) {
        bf16x8 kf = *(const bf16x8*)&Kc[koff * 64 + (((ds * 2 + hi) ^ (koff & 7)) << 3)];
        acc = __builtin_amdgcn_mfma_f32_32x32x16_bf16(kf, aq[ds], acc, 0, 0, 0);
      }
      s[kb] = acc;
    }
    __builtin_amdgcn_s_setprio(0);

    float v8[8];
    #pragma unroll
    for (int i = 0; i < 8; i++)
      v8[i] = fmaxf(fmaxf(s[0][i], s[0][i + 8]), fmaxf(s[1][i], s[1][i + 8]));
    float m_in = fmaxf(fmaxf(fmaxf(v8[0], v8[1]), fmaxf(v8[2], v8[3])),
                       fmaxf(fmaxf(v8[4], v8[5]), fmaxf(v8[6], v8[7])));
    u32 xa = __float_as_uint(m_in), xb = __float_as_uint(m_in);
    plswap(xa, xb);
    float m_tile = fmaxf(__uint_as_float(xa), __uint_as_float(xb));
    float mnew = fmaxf(m_run, m_tile);
    float alpha = fexp2(m_run - mnew);
    m_run = mnew;

    float c0 = 0.f, c1 = 0.f, c2 = 0.f, c3 = 0.f;
    #pragma unroll
    for (int kb = 0; kb < 2; kb++)
      #pragma unroll
      for (int i = 0; i < 16; i++) {
        float e = fexp2(s[kb][i] - mnew);
        s[kb][i] = e;
        if ((i & 3) == 0) c0 += e; else if ((i & 3) == 1) c1 += e;
        else if ((i & 3) == 2) c2 += e; else c3 += e;
      }
    float cs = (c0 + c1) + (c2 + c3);
    u32 ya = __float_as_uint(cs), yb = __float_as_uint(cs);
    plswap(ya, yb);
    float cs_tot = __uint_as_float(ya) + __uint_as_float(yb);
    l_run = l_run * alpha + cs_tot;

    #pragma unroll
    for (int dt = 0; dt < 2; dt++) o[dt] *= alpha;

    __builtin_amdgcn_s_setprio(1);
    #pragma unroll
    for (int ks = 0; ks < 4; ks++) {
      int kb = ks >> 1, j4 = (ks & 1) * 8;
      u32 a0 = pkbf(s[kb][j4 + 0], s[kb][j4 + 1]);
      u32 a1 = pkbf(s[kb][j4 + 2], s[kb][j4 + 3]);
      u32 b0 = pkbf(s[kb][j4 + 4], s[kb][j4 + 5]);
      u32 b1 = pkbf(s[kb][j4 + 6], s[kb][j4 + 7]);
      plswap(a0, b0);
      plswap(a1, b1);
      union { u32 w[4]; bf16x8 v; } U;
      U.w[0] = a0; U.w[1] = a1; U.w[2] = b0; U.w[3] = b1;
      #pragma unroll
      for (int dt = 0; dt < 2; dt++) {
        int dr = dt * 32 + l31;
        bf16x8 vf = *(const bf16x8*)&Vc[dr * 64 + (((ks * 2 + hi) ^ (dr & 7)) << 3)];
        o[dt] = __builtin_amdgcn_mfma_f32_32x32x16_bf16(vf, U.v, o[dt], 0, 0, 0);
      }
    }
    __builtin_amdgcn_s_setprio(0);

    __syncthreads();
    cur ^= 1;
  }

  float linv = 1.0f / l_run;
  u16* Ow = smem + wave * 2304;   // [32 q][72 d] u16
  #pragma unroll
  for (int dt = 0; dt < 2; dt++)
    #pragma unroll
    for (int g = 0; g < 4; g++) {
      u32 w0 = pkbf(o[dt][4 * g + 0] * linv, o[dt][4 * g + 1] * linv);
      u32 w1 = pkbf(o[dt][4 * g + 2] * linv, o[dt][4 * g + 3] * linv);
      uint2 pr; pr.x = w0; pr.y = w1;
      *(uint2*)&Ow[l31 * 72 + dt * 32 + g * 8 + hi * 4] = pr;
    }
  #pragma unroll
  for (int i = 0; i < 4; i++) {
    int idx = i * 64 + lane;
    int row = idx >> 3, seg = idx & 7;
    bf16x8 val = *(const bf16x8*)&Ow[row * 72 + seg * 8];
    *(bf16x8*)(attn16 + ((size_t)b * 512 + qb + row) * 1024 + h * 64 + seg * 8) = val;
  }
}

// ---------------------------------------------------------------- launch
extern "C" void kernel_launch(void* const* d_in, const int* in_sizes, int n_in,
                              void* d_out, int out_size, void* d_ws, size_t ws_size,
                              hipStream_t stream) {
  const float* hR  = (const float*)d_in[0];
  const float* R   = (const float*)d_in[1];
  const float* Wq  = (const float*)d_in[2];
  const float* Wk  = (const float*)d_in[3];
  const float* Wv  = (const float*)d_in[4];
  const float* Wo  = (const float*)d_in[5];
  const float* wsm = (const float*)d_in[6];
  float* out = (float*)d_out;

  const size_t NE = 16777216;   // 16384 x 1024
  u16* ws16   = (u16*)d_ws;
  u16* hR16   = ws16;
  u16* attn16 = ws16;           // reuses hR16 (consumed by QKV GEMM)
  u16* q16    = ws16 + NE;
  u16* k16    = ws16 + 2 * NE;
  u16* v16    = ws16 + 3 * NE;
  u16* vt16   = ws16 + 4 * NE;
  u16* Wq16   = ws16 + 5 * NE;
  u16* Wk16   = Wq16 + 1048576;
  u16* Wv16   = Wk16 + 1048576;
  u16* Wo16   = Wv16 + 1048576;
  u16* sim16  = Wo16 + 1048576;              // 512*512 bf16
  float* Rn   = (float*)(sim16 + 262144);    // 512*256 fp32

  convert_kernel<<<20480, 256, 0, stream>>>(hR, Wq, Wk, Wv, Wo,
                                            hR16, Wq16, Wk16, Wv16, Wo16);
  rnorm_kernel<<<512, 64, 0, stream>>>(R, Rn);
  sim_kernel<<<32, 256, 0, stream>>>(Rn, sim16);
  gemm_kernel<0><<<dim3(64, 12), 512, 0, stream>>>(hR16, Wq16, Wk16, Wv16,
                                                   q16, k16, v16, nullptr);
  vtrans_kernel<<<dim3(8, 512), 256, 0, stream>>>(v16, vt16);
  attn_kernel<<<2048, 256, 0, stream>>>(q16, k16, vt16, sim16, wsm, attn16);
  gemm_kernel<1><<<dim3(64, 4), 512, 0, stream>>>(attn16, Wo16, nullptr, nullptr,
                                                  nullptr, nullptr, nullptr, out);
}

// Round 7
// 415.523 us; speedup vs baseline: 1.1164x; 1.0413x over previous
//
#include <hip/hip_runtime.h>

#define SEQK 512
#define NH 16
#define HD 64
#define RD 1024
#define BBATCH 32
#define QK_SCALE 0.125f        // 1/sqrt(64)
#define LOG2E 1.4426950408889634f

typedef unsigned short u16;
typedef unsigned int u32;
using bf16x8 = __attribute__((ext_vector_type(8))) short;
using f32x4  = __attribute__((ext_vector_type(4))) float;
using f32x16 = __attribute__((ext_vector_type(16))) float;

__device__ __forceinline__ u16 f2bf(float f) {
  unsigned u = __float_as_uint(f);
  u += 0x7FFFu + ((u >> 16) & 1u);   // round-to-nearest-even
  return (u16)(u >> 16);
}
__device__ __forceinline__ float bf2f(u16 v) {
  return __uint_as_float(((unsigned)v) << 16);
}
// 2^x in one VALU op (inputs are pre-scaled by LOG2E upstream)
__device__ __forceinline__ float fexp2(float x) {
  float r;
  asm("v_exp_f32 %0, %1" : "=v"(r) : "v"(x));
  return r;
}
// packed f32x2 -> bf16x2 (RNE), lo in [15:0], hi in [31:16]  (m240 recipe)
__device__ __forceinline__ u32 pkbf(float lo, float hi) {
  u32 r;
  asm("v_cvt_pk_bf16_f32 %0, %1, %2" : "=v"(r) : "v"(lo), "v"(hi));
  return r;
}
// swap a's upper 32 lanes with b's lower 32 lanes (gfx950 permlane32_swap)
__device__ __forceinline__ void plswap(u32& a, u32& b) {
#if __has_builtin(__builtin_amdgcn_permlane32_swap)
  typedef int v2i __attribute__((ext_vector_type(2)));
  v2i r = __builtin_amdgcn_permlane32_swap((int)a, (int)b, false, false);
  a = (u32)r[0]; b = (u32)r[1];
#else
  asm volatile("v_permlane32_swap_b32 %0, %1" : "+v"(a), "+v"(b));
#endif
}

__device__ __forceinline__ void async_cp16(const void* g, void* l) {
  __builtin_amdgcn_global_load_lds(
      (__attribute__((address_space(1))) void*)(void*)g,
      (__attribute__((address_space(3))) void*)l,
      16, 0, 0);
}

// ---------------------------------------------------------------- convert
__global__ void convert_kernel(const float* __restrict__ hR,
                               const float* __restrict__ Wq, const float* __restrict__ Wk,
                               const float* __restrict__ Wv, const float* __restrict__ Wo,
                               u16* __restrict__ hR16,
                               u16* __restrict__ Wq16, u16* __restrict__ Wk16,
                               u16* __restrict__ Wv16, u16* __restrict__ Wo16) {
  size_t i4 = (size_t)blockIdx.x * blockDim.x + threadIdx.x;
  size_t e = i4 * 4;
  const float* src; u16* dst; size_t off;
  if (e < 16777216u) { src = hR; dst = hR16; off = e; }
  else {
    size_t r = e - 16777216u;
    int w = (int)(r >> 20);
    off = r & 1048575u;
    src = (w == 0 ? Wq : w == 1 ? Wk : w == 2 ? Wv : Wo);
    dst = (w == 0 ? Wq16 : w == 1 ? Wk16 : w == 2 ? Wv16 : Wo16);
  }
  float4 v = *(const float4*)(src + off);
  ushort4 o;
  o.x = f2bf(v.x); o.y = f2bf(v.y); o.z = f2bf(v.z); o.w = f2bf(v.w);
  *(ushort4*)(dst + off) = o;
}

// ---------------------------------------------------------------- R normalize
__global__ void rnorm_kernel(const float* __restrict__ R, float* __restrict__ Rn) {
  int row = blockIdx.x;
  int lane = threadIdx.x;
  float4 v = *(const float4*)(R + (size_t)row * 256 + lane * 4);
  float ss = v.x * v.x + v.y * v.y + v.z * v.z + v.w * v.w;
  for (int off = 32; off; off >>= 1) ss += __shfl_xor(ss, off);
  float s = 1.0f / fmaxf(sqrtf(ss), 1e-12f);
  float4 o = {v.x * s, v.y * s, v.z * s, v.w * s};
  *(float4*)(Rn + (size_t)row * 256 + lane * 4) = o;
}

// ---------------------------------------------------------------- sim = Rn @ Rn^T  (bf16 out)
__global__ void sim_kernel(const float* __restrict__ Rn, u16* __restrict__ sim16) {
  __shared__ float Rl[16 * 256];
  int i0 = blockIdx.x * 16;
  int t = threadIdx.x;
  #pragma unroll
  for (int i = 0; i < 4; i++) {
    int f = t + i * 256;
    *(float4*)&Rl[f * 4] = *(const float4*)(Rn + (size_t)i0 * 256 + f * 4);
  }
  __syncthreads();
  for (int jj = 0; jj < 2; jj++) {
    int j = jj * 256 + t;
    float acc[16];
    #pragma unroll
    for (int i = 0; i < 16; i++) acc[i] = 0.f;
    for (int c = 0; c < 64; c++) {
      float4 rv = *(const float4*)(Rn + (size_t)j * 256 + c * 4);
      #pragma unroll
      for (int i = 0; i < 16; i++) {
        float4 a = *(const float4*)&Rl[i * 256 + c * 4];
        acc[i] += a.x * rv.x + a.y * rv.y + a.z * rv.z + a.w * rv.w;
      }
    }
    #pragma unroll
    for (int i = 0; i < 16; i++) sim16[(size_t)(i0 + i) * 512 + j] = f2bf(acc[i]);
  }
}

// ---------------------------------------------------------------- GEMM: 256^2, 4-phase, B-in-reg
// R6 post-mortem: swizzle fixed (conflicts 18.9M->0) but MfmaUtil stuck at 34%
// — the 8-phase quadrant macro LOADED EVERY FRAGMENT TWICE (A per NH, B per
// MH): 48 ds_read_b128/K-tile/wave. LDS pipe demand 48*8waves*~8cy = 3.1k cy
// > MFMA 512*4.85 = 2.5k cy per CU per K-tile -> LDS-read-BW-bound (matches
// 131us = 38% MFMA floor). Fix: 2 phases per K-tile, minimum 24 reads:
//   EVEN phase: read A-S0 (8) + ALL B (8) -> 32 MFMA (acc rows 0-3 x all N)
//   ODD  phase: read A-S1 (8); B REUSED from registers -> 32 MFMA (rows 4-7)
// Now LDS 24*8*8=1.5k cy < MFMA 2.5k cy -> MFMA-bound. +32 VGPR for held B
// (~220 total; 1 block/CU is LDS-bound so VGPR<=256 free).
//
// Stage/vmcnt ladder (iter i: t0=2i in buf0, t1=2i+1 in buf1; each phase
// stages 2 half-tiles = 4 loads/thread):
//   ph0 (t0 MH0; reads As0-S0,Bs0): stage A-S1(t1),B-T1(t1)->buf1
//       [buf1 S1/T1 last read prev ph3/ph2 — barrier-separated]
//   ph1 (t0 MH1; reads As0-S1): stage A-S0(t0+2),B-T0(t0+2)->buf0
//       end: vmcnt(4) retires prev-ph3(t1 S0/T0)+ph0(t1 S1/T1) -> t1 resident
//       for ph2; leaves ph1's 4. (!more: vmcnt(0).)
//   ph2 (t1 MH0; reads As1-S0,Bs1): stage A-S1(t0+2),B-T1(t0+2)->buf0
//   ph3 (t1 MH1; reads As1-S1): stage A-S0(t1+2),B-T0(t1+2)->buf1
//       end: vmcnt(4) retires ph1+ph2 (t0+2 complete) for next ph0.
// vmcnt never 0 in steady state; raw s_barrier; per-acc K-order unchanged.
#define GEMM_PHASE_E(AB, BB, STAGE, WAITSTMT) {                               \
    bf16x8 af[4][2];                                                          \
    _Pragma("unroll") for (int mi2 = 0; mi2 < 4; mi2++) {                     \
      int r = wm * 128 + mi2 * 16 + lr;                                       \
      int sw = r & 7;                                                         \
      _Pragma("unroll") for (int ks = 0; ks < 2; ks++)                        \
        af[mi2][ks] = *(const bf16x8*)&(AB)[r * 64 + ((ks * 4 + qd) ^ sw) * 8]; \
    }                                                                         \
    _Pragma("unroll") for (int nj = 0; nj < 4; nj++) {                        \
      int r = wn * 64 + nj * 16 + lr;                                         \
      int sw = r & 7;                                                         \
      _Pragma("unroll") for (int ks = 0; ks < 2; ks++)                        \
        bq[nj][ks] = *(const bf16x8*)&(BB)[r * 64 + ((ks * 4 + qd) ^ sw) * 8]; \
    }                                                                         \
    STAGE;                                                                    \
    __builtin_amdgcn_sched_barrier(0);                                        \
    __builtin_amdgcn_s_barrier();                                             \
    __builtin_amdgcn_sched_barrier(0);                                        \
    __builtin_amdgcn_s_setprio(1);                                            \
    _Pragma("unroll") for (int mi2 = 0; mi2 < 4; mi2++)                       \
      _Pragma("unroll") for (int nj = 0; nj < 4; nj++)                        \
        _Pragma("unroll") for (int ks = 0; ks < 2; ks++)                      \
          acc[mi2][nj] = __builtin_amdgcn_mfma_f32_16x16x32_bf16(             \
              af[mi2][ks], bq[nj][ks], acc[mi2][nj], 0, 0, 0);                \
    __builtin_amdgcn_s_setprio(0);                                            \
    WAITSTMT;                                                                 \
    __builtin_amdgcn_sched_barrier(0);                                        \
    __builtin_amdgcn_s_barrier();                                             \
  }

#define GEMM_PHASE_O(AB, STAGE, WAITSTMT) {                                   \
    bf16x8 af[4][2];                                                          \
    _Pragma("unroll") for (int mi2 = 0; mi2 < 4; mi2++) {                     \
      int r = wm * 128 + 64 + mi2 * 16 + lr;                                  \
      int sw = r & 7;                                                         \
      _Pragma("unroll") for (int ks = 0; ks < 2; ks++)                        \
        af[mi2][ks] = *(const bf16x8*)&(AB)[r * 64 + ((ks * 4 + qd) ^ sw) * 8]; \
    }                                                                         \
    STAGE;                                                                    \
    __builtin_amdgcn_sched_barrier(0);                                        \
    __builtin_amdgcn_s_barrier();                                             \
    __builtin_amdgcn_sched_barrier(0);                                        \
    __builtin_amdgcn_s_setprio(1);                                            \
    _Pragma("unroll") for (int mi2 = 0; mi2 < 4; mi2++)                       \
      _Pragma("unroll") for (int nj = 0; nj < 4; nj++)                        \
        _Pragma("unroll") for (int ks = 0; ks < 2; ks++)                      \
          acc[4 + mi2][nj] = __builtin_amdgcn_mfma_f32_16x16x32_bf16(         \
              af[mi2][ks], bq[nj][ks], acc[4 + mi2][nj], 0, 0, 0);            \
    __builtin_amdgcn_s_setprio(0);                                            \
    WAITSTMT;                                                                 \
    __builtin_amdgcn_sched_barrier(0);                                        \
    __builtin_amdgcn_s_barrier();                                             \
  }

template <int MODE>
__global__ __launch_bounds__(512, 2)
void gemm_kernel(const u16* __restrict__ A,
                 const u16* __restrict__ B0, const u16* __restrict__ B1,
                 const u16* __restrict__ B2,
                 u16* __restrict__ q16, u16* __restrict__ k16, u16* __restrict__ v16,
                 float* __restrict__ outF) {
  __shared__ u16 smem[65536];        // 128 KB
  u16* const As0 = smem;
  u16* const As1 = smem + 16384;
  u16* const Bs0 = smem + 32768;
  u16* const Bs1 = smem + 49152;

  int tid = threadIdx.x;
  int wave = tid >> 6, lane = tid & 63;
  int wm = wave >> 2, wn = wave & 3;
  int lr = lane & 15, qd = lane >> 4;
  int mb = blockIdx.x * 256;
  int ny = blockIdx.y;

  const u16* Bmat;
  int nbase;
  if (MODE == 0) {
    int wsel = ny >> 2;
    Bmat = (wsel == 0 ? B0 : wsel == 1 ? B1 : B2);
    nbase = (ny & 3) * 256;
  } else {
    Bmat = B0;
    nbase = ny * 256;
  }
  const u16* Ag = A + (size_t)mb * 1024;
  const u16* Bg = Bmat + (size_t)nbase * 1024;

  // stage one A half-tile (128 rows: blocks {half,half+2} of 64) of K-tile
  // at gsrc into LDS tile dst. Linear LDS dest (wave-uniform base + lane*16);
  // 3-bit swizzle on the global source chunk (involution, matches reads).
  auto stageA_ = [&](u16* dst, const u16* gsrc, int half) {
    int blk = ((wave < 4) ? 0 : 2) + half;
    int ws = wave & 3;
    #pragma unroll
    for (int jj = 0; jj < 2; jj++) {
      int rbase = blk * 64 + ws * 16 + jj * 8;
      int row = rbase + (lane >> 3);
      int c8 = (lane & 7) ^ (row & 7);
      async_cp16(gsrc + (size_t)row * 1024 + c8 * 8, dst + rbase * 64);
    }
  };
  // B half-tile: rows {st*64 + half*32 .. +31} for st=0..3
  auto stageB_ = [&](u16* dst, const u16* gsrc, int half) {
    int st = wave >> 1, sub = wave & 1;
    #pragma unroll
    for (int jj = 0; jj < 2; jj++) {
      int rbase = st * 64 + half * 32 + sub * 16 + jj * 8;
      int row = rbase + (lane >> 3);
      int c8 = (lane & 7) ^ (row & 7);
      async_cp16(gsrc + (size_t)row * 1024 + c8 * 8, dst + rbase * 64);
    }
  };

  f32x4 acc[8][4];
  #pragma unroll
  for (int i = 0; i < 8; i++)
    #pragma unroll
    for (int j = 0; j < 4; j++) acc[i][j] = f32x4{0.f, 0.f, 0.f, 0.f};

  // prologue: full K-tile 0 + halves S0/T0 of K-tile 1 (12 loads/thread)
  stageA_(As0, Ag, 0);
  stageB_(Bs0, Bg, 0);
  stageA_(As0, Ag, 1);
  stageB_(Bs0, Bg, 1);
  stageA_(As1, Ag + 64, 0);
  stageB_(Bs1, Bg + 64, 0);
  asm volatile("s_waitcnt vmcnt(4)" ::: "memory");   // K-tile 0 landed
  __builtin_amdgcn_sched_barrier(0);
  __builtin_amdgcn_s_barrier();

  #pragma unroll 1
  for (int i = 0; i < 8; i++) {
    int t1 = 2 * i + 1;
    bool more = (i < 7);
    const u16* Ag1 = Ag + t1 * 64;
    const u16* Bg1 = Bg + t1 * 64;
    const u16* Ag2 = Ag + (t1 + 1) * 64;
    const u16* Bg2 = Bg + (t1 + 1) * 64;
    const u16* Ag3 = Ag + (t1 + 2) * 64;
    const u16* Bg3 = Bg + (t1 + 2) * 64;

    bf16x8 bq[4][2];   // B fragments held across the E->O phase pair

    // ph0: t0 MH0 ; stage t1 S1/T1 -> buf1
    GEMM_PHASE_E(As0, Bs0,
                 { stageA_(As1, Ag1, 1); stageB_(Bs1, Bg1, 1); }, {});
    // ph1: t0 MH1 ; stage t0+2 S0/T0 -> buf0 ; retire t1's staging
    GEMM_PHASE_O(As0,
                 { if (more) { stageA_(As0, Ag2, 0); stageB_(Bs0, Bg2, 0); } },
                 { if (more) asm volatile("s_waitcnt vmcnt(4)" ::: "memory");
                   else      asm volatile("s_waitcnt vmcnt(0)" ::: "memory"); });
    // ph2: t1 MH0 ; stage t0+2 S1/T1 -> buf0
    GEMM_PHASE_E(As1, Bs1,
                 { if (more) { stageA_(As0, Ag2, 1); stageB_(Bs0, Bg2, 1); } }, {});
    // ph3: t1 MH1 ; stage t1+2 S0/T0 -> buf1 ; retire t0+2's staging
    GEMM_PHASE_O(As1,
                 { if (more) { stageA_(As1, Ag3, 0); stageB_(Bs1, Bg3, 0); } },
                 { if (more) asm volatile("s_waitcnt vmcnt(4)" ::: "memory"); });
  }

  if (MODE == 0) {
    int wsel = ny >> 2;
    u16* dst = (wsel == 0 ? q16 : wsel == 1 ? k16 : v16);
    // Q gets 1/sqrt(D)*log2(e): scores land in the exp2 domain.
    float scl = (wsel == 0) ? QK_SCALE * LOG2E : 1.0f;
    #pragma unroll
    for (int mi = 0; mi < 8; mi++) {
      int m = mb + wm * 128 + mi * 16 + qd * 4;
      int b = m >> 9, kk = m & 511;
      #pragma unroll
      for (int ni = 0; ni < 4; ni++) {
        int n = nbase + wn * 64 + ni * 16 + lr;
        int h = n >> 6, d = n & 63;
        u16* p = dst + ((size_t)(b * 16 + h) * 512 + kk) * 64 + d;
        #pragma unroll
        for (int r = 0; r < 4; r++) p[(size_t)r * 64] = f2bf(acc[mi][ni][r] * scl);
      }
    }
  } else {
    #pragma unroll
    for (int mi = 0; mi < 8; mi++) {
      int m = mb + wm * 128 + mi * 16 + qd * 4;
      #pragma unroll
      for (int ni = 0; ni < 4; ni++) {
        int n = nbase + wn * 64 + ni * 16 + lr;
        #pragma unroll
        for (int r = 0; r < 4; r++) outF[(size_t)(m + r) * 1024 + n] = acc[mi][ni][r];
      }
    }
  }
}

// ---------------------------------------------------------------- V transpose
__global__ void vtrans_kernel(const u16* __restrict__ v16, u16* __restrict__ vt16) {
  __shared__ u16 tile[64 * 72];
  int kt = blockIdx.x;
  int bh = blockIdx.y;
  int t = threadIdx.x;
  const u16* src = v16 + ((size_t)bh * 512 + kt * 64) * 64;
  #pragma unroll
  for (int j = 0; j < 2; j++) {
    int linear = j * 2048 + t * 8;
    int kr = linear >> 6, d0 = linear & 63;
    bf16x8 vv = *(const bf16x8*)(src + (size_t)kr * 64 + d0);
    #pragma unroll
    for (int e = 0; e < 8; e++) tile[kr * 72 + d0 + e] = (u16)vv[e];
  }
  __syncthreads();
  #pragma unroll
  for (int j = 0; j < 2; j++) {
    int linear = j * 2048 + t * 8;
    int dr = linear >> 6, k0 = linear & 63;
    bf16x8 ov;
    #pragma unroll
    for (int e = 0; e < 8; e++) ov[e] = (short)tile[(k0 + e) * 72 + dr];
    *(bf16x8*)(vt16 + ((size_t)bh * 64 + dr) * 512 + kt * 64 + k0) = ov;
  }
}

// ---------------------------------------------------------------- fused attention v6b
// (unchanged — verified: T12 in-register softmax via swapped 32x32 QK^T,
// permlane32_swap stats + P fragments, counted-vmcnt K/V prefetch)
__global__ __launch_bounds__(256, 3)
void attn_kernel(const u16* __restrict__ q16, const u16* __restrict__ k16,
                 const u16* __restrict__ vt16, const u16* __restrict__ sim16,
                 const float* __restrict__ wsim, u16* __restrict__ attn16) {
  __shared__ u16 smem[16384];   // 32 KB: K dbuf [2][64*64] + Vt dbuf [2][64*64]

  int id = blockIdx.x;
  int xcd = id & 7;
  int j = id >> 3;
  int qt = j & 3;
  int bh = xcd * 64 + (j >> 2);
  int b = bh >> 4, h = bh & 15;

  int tid = threadIdx.x;
  int wave = tid >> 6, lane = tid & 63;
  int l31 = lane & 31, hi = lane >> 5;
  int qb = qt * 128 + wave * 32;        // this wave's 32 q rows

  const u16* qp = q16 + ((size_t)bh * 512 + qb + l31) * 64 + hi * 8;
  bf16x8 aq[4];
  #pragma unroll
  for (int ds = 0; ds < 4; ds++) aq[ds] = *(const bf16x8*)(qp + ds * 16);

  float ws = wsim[h] * LOG2E;           // bias in exp2 domain

  f32x16 o[2];
  #pragma unroll
  for (int dt = 0; dt < 2; dt++)
    #pragma unroll
    for (int r = 0; r < 16; r++) o[dt][r] = 0.f;
  float m_run = -1e30f, l_run = 0.f;

  const u16* kbase = k16 + (size_t)bh * 512 * 64;
  const u16* vbase = vt16 + (size_t)bh * 64 * 512;

  auto stage = [&](int nb, int ck) {
    int k0 = ck * 64;
    u16* kd = smem + nb * 4096;
    u16* vd = smem + 8192 + nb * 4096;
    #pragma unroll
    for (int it = 0; it < 2; it++) {
      int idx = it * 256 + wave * 64 + lane;
      int r = idx >> 3, c8 = idx & 7;
      async_cp16(kbase + (size_t)(k0 + r) * 64 + ((c8 ^ (r & 7)) << 3),
                 kd + (it * 256 + wave * 64) * 8);
    }
    #pragma unroll
    for (int it = 0; it < 2; it++) {
      int idx = it * 256 + wave * 64 + lane;
      int dr = idx >> 3, c8 = idx & 7;
      async_cp16(vbase + (size_t)dr * 512 + k0 + ((c8 ^ (dr & 7)) << 3),
                 vd + (it * 256 + wave * 64) * 8);
    }
  };

  stage(0, 0);
  __syncthreads();

  int cur = 0;
  for (int ck = 0; ck < 8; ck++) {
    int k0 = ck * 64;

    uint2 braw[8];
    #pragma unroll
    for (int kb = 0; kb < 2; kb++)
      #pragma unroll
      for (int g = 0; g < 4; g++)
        braw[kb * 4 + g] = *(const uint2*)(sim16 + (size_t)(qb + l31) * 512 +
                                           k0 + kb * 32 + g * 8 + hi * 4);
    __builtin_amdgcn_sched_barrier(0);
    if (ck < 7) stage(cur ^ 1, ck + 1);

    const u16* Kc = smem + cur * 4096;
    const u16* Vc = smem + 8192 + cur * 4096;

    f32x16 s[2];
    __builtin_amdgcn_s_setprio(1);
    #pragma unroll
    for (int kb = 0; kb < 2; kb++) {
      f32x16 acc;
      #pragma unroll
      for (int r = 0; r < 16; r++) {
        u32 w = ((r >> 1) & 1) ? braw[kb * 4 + (r >> 2)].y
                               : braw[kb * 4 + (r >> 2)].x;
        acc[r] = ws * __uint_as_float((r & 1) ? (w & 0xFFFF0000u) : (w << 16));
      }
      int koff = kb * 32 + l31;
      #pragma unroll
      for (int ds = 0; ds < 4; ds++) {
        bf16x8 kf = *(const bf16x8*)&Kc[koff * 64 + (((ds * 2 + hi) ^ (koff & 7)) << 3)];
        acc = __builtin_amdgcn_mfma_f32_32x32x16_bf16(kf, aq[ds], acc, 0, 0, 0);
      }
      s[kb] = acc;
    }
    __builtin_amdgcn_s_setprio(0);

    float v8[8];
    #pragma unroll
    for (int i = 0; i < 8; i++)
      v8[i] = fmaxf(fmaxf(s[0][i], s[0][i + 8]), fmaxf(s[1][i], s[1][i + 8]));
    float m_in = fmaxf(fmaxf(fmaxf(v8[0], v8[1]), fmaxf(v8[2], v8[3])),
                       fmaxf(fmaxf(v8[4], v8[5]), fmaxf(v8[6], v8[7])));
    u32 xa = __float_as_uint(m_in), xb = __float_as_uint(m_in);
    plswap(xa, xb);
    float m_tile = fmaxf(__uint_as_float(xa), __uint_as_float(xb));
    float mnew = fmaxf(m_run, m_tile);
    float alpha = fexp2(m_run - mnew);
    m_run = mnew;

    float c0 = 0.f, c1 = 0.f, c2 = 0.f, c3 = 0.f;
    #pragma unroll
    for (int kb = 0; kb < 2; kb++)
      #pragma unroll
      for (int i = 0; i < 16; i++) {
        float e = fexp2(s[kb][i] - mnew);
        s[kb][i] = e;
        if ((i & 3) == 0) c0 += e; else if ((i & 3) == 1) c1 += e;
        else if ((i & 3) == 2) c2 += e; else c3 += e;
      }
    float cs = (c0 + c1) + (c2 + c3);
    u32 ya = __float_as_uint(cs), yb = __float_as_uint(cs);
    plswap(ya, yb);
    float cs_tot = __uint_as_float(ya) + __uint_as_float(yb);
    l_run = l_run * alpha + cs_tot;

    #pragma unroll
    for (int dt = 0; dt < 2; dt++) o[dt] *= alpha;

    __builtin_amdgcn_s_setprio(1);
    #pragma unroll
    for (int ks = 0; ks < 4; ks++) {
      int kb = ks >> 1, j4 = (ks & 1) * 8;
      u32 a0 = pkbf(s[kb][j4 + 0], s[kb][j4 + 1]);
      u32 a1 = pkbf(s[kb][j4 + 2], s[kb][j4 + 3]);
      u32 b0 = pkbf(s[kb][j4 + 4], s[kb][j4 + 5]);
      u32 b1 = pkbf(s[kb][j4 + 6], s[kb][j4 + 7]);
      plswap(a0, b0);
      plswap(a1, b1);
      union { u32 w[4]; bf16x8 v; } U;
      U.w[0] = a0; U.w[1] = a1; U.w[2] = b0; U.w[3] = b1;
      #pragma unroll
      for (int dt = 0; dt < 2; dt++) {
        int dr = dt * 32 + l31;
        bf16x8 vf = *(const bf16x8*)&Vc[dr * 64 + (((ks * 2 + hi) ^ (dr & 7)) << 3)];
        o[dt] = __builtin_amdgcn_mfma_f32_32x32x16_bf16(vf, U.v, o[dt], 0, 0, 0);
      }
    }
    __builtin_amdgcn_s_setprio(0);

    __syncthreads();
    cur ^= 1;
  }

  float linv = 1.0f / l_run;
  u16* Ow = smem + wave * 2304;   // [32 q][72 d] u16
  #pragma unroll
  for (int dt = 0; dt < 2; dt++)
    #pragma unroll
    for (int g = 0; g < 4; g++) {
      u32 w0 = pkbf(o[dt][4 * g + 0] * linv, o[dt][4 * g + 1] * linv);
      u32 w1 = pkbf(o[dt][4 * g + 2] * linv, o[dt][4 * g + 3] * linv);
      uint2 pr; pr.x = w0; pr.y = w1;
      *(uint2*)&Ow[l31 * 72 + dt * 32 + g * 8 + hi * 4] = pr;
    }
  #pragma unroll
  for (int i = 0; i < 4; i++) {
    int idx = i * 64 + lane;
    int row = idx >> 3, seg = idx & 7;
    bf16x8 val = *(const bf16x8*)&Ow[row * 72 + seg * 8];
    *(bf16x8*)(attn16 + ((size_t)b * 512 + qb + row) * 1024 + h * 64 + seg * 8) = val;
  }
}

// ---------------------------------------------------------------- launch
extern "C" void kernel_launch(void* const* d_in, const int* in_sizes, int n_in,
                              void* d_out, int out_size, void* d_ws, size_t ws_size,
                              hipStream_t stream) {
  const float* hR  = (const float*)d_in[0];
  const float* R   = (const float*)d_in[1];
  const float* Wq  = (const float*)d_in[2];
  const float* Wk  = (const float*)d_in[3];
  const float* Wv  = (const float*)d_in[4];
  const float* Wo  = (const float*)d_in[5];
  const float* wsm = (const float*)d_in[6];
  float* out = (float*)d_out;

  const size_t NE = 16777216;   // 16384 x 1024
  u16* ws16   = (u16*)d_ws;
  u16* hR16   = ws16;
  u16* attn16 = ws16;           // reuses hR16 (consumed by QKV GEMM)
  u16* q16    = ws16 + NE;
  u16* k16    = ws16 + 2 * NE;
  u16* v16    = ws16 + 3 * NE;
  u16* vt16   = ws16 + 4 * NE;
  u16* Wq16   = ws16 + 5 * NE;
  u16* Wk16   = Wq16 + 1048576;
  u16* Wv16   = Wk16 + 1048576;
  u16* Wo16   = Wv16 + 1048576;
  u16* sim16  = Wo16 + 1048576;              // 512*512 bf16
  float* Rn   = (float*)(sim16 + 262144);    // 512*256 fp32

  convert_kernel<<<20480, 256, 0, stream>>>(hR, Wq, Wk, Wv, Wo,
                                            hR16, Wq16, Wk16, Wv16, Wo16);
  rnorm_kernel<<<512, 64, 0, stream>>>(R, Rn);
  sim_kernel<<<32, 256, 0, stream>>>(Rn, sim16);
  gemm_kernel<0><<<dim3(64, 12), 512, 0, stream>>>(hR16, Wq16, Wk16, Wv16,
                                                   q16, k16, v16, nullptr);
  vtrans_kernel<<<dim3(8, 512), 256, 0, stream>>>(v16, vt16);
  attn_kernel<<<2048, 256, 0, stream>>>(q16, k16, vt16, sim16, wsm, attn16);
  gemm_kernel<1><<<dim3(64, 4), 512, 0, stream>>>(attn16, Wo16, nullptr, nullptr,
                                                  nullptr, nullptr, nullptr, out);
}